// Round 16
// baseline (2561.377 us; speedup 1.0000x reference)
//
#include <hip/hip_runtime.h>
#include <math.h>

typedef __bf16 bf16x8 __attribute__((ext_vector_type(8)));
typedef float f32x4 __attribute__((ext_vector_type(4)));
typedef unsigned int u32x4 __attribute__((ext_vector_type(4)));
typedef unsigned long long u64;

constexpr int QQ = 1027;   // states
constexpr int SS = 26;     // alphabet
constexpr int TT = 512;    // sequence length
constexpr int NB = 256;    // batch
constexpr int KP = 1056;   // K padded in LDS (33 ksteps of 32)
constexpr int NP = 1040;   // N padded (65 tiles of 16) = exchanged row length
constexpr int BTS = 1040;  // Bt row stride (floats)
constexpr int NSL = 13;    // N slices (5 tiles = 80 cols each)
constexpr int NBB = 16;    // batch blocks
constexpr int MB = 16;     // batch rows per block
constexpr int NWV = 5;     // waves per WG (1 col-tile each)
constexpr int CBLK = NWV * 64;       // 320
constexpr int KSTEPS = 33;
constexpr int BSQ = NP / 4;          // 260 u64 col-quads per batch row
constexpr int TOTQ = MB * BSQ;       // 4160 u64 per batch-block alpha
constexpr int BUFQ = NBB * TOTQ;     // 66560 u64 per slot
constexpr int LQ = 274;              // u64 LDS row stride
constexpr int NPAIR = TOTQ / 2;      // 2080 u64-pairs per block
constexpr int PFULL = 6;             // full x4-loads per thread (6*320=1920 pairs)
constexpr int PREM = NPAIR - PFULL * CBLK;  // 160 threads do a 7th pair
constexpr u64 SMASK = 0x7FFF7FFF7FFF7FFFull;

__device__ __forceinline__ unsigned short f2bf(float f) {
  union { float f; unsigned u; } v; v.f = f;
  return (unsigned short)((v.u + 0x7fffu + ((v.u >> 16) & 1u)) >> 16);
}

__device__ __forceinline__ u64 ald8(const u64* p) {
  return __hip_atomic_load((u64*)p, __ATOMIC_RELAXED, __HIP_MEMORY_SCOPE_AGENT);
}
__device__ __forceinline__ void ast8(u64* p, u64 v) {
  __hip_atomic_store(p, v, __ATOMIC_RELAXED, __HIP_MEMORY_SCOPE_AGENT);
}

__device__ __forceinline__ float sum4bf(u64 q) {
  union { unsigned u; float f; } a, b, c, d;
  a.u = ((unsigned)(q & 0xFFFFu)) << 16;
  b.u = ((unsigned)((q >> 16) & 0xFFFFu)) << 16;
  c.u = ((unsigned)((q >> 32) & 0xFFFFu)) << 16;
  d.u = ((unsigned)((q >> 48) & 0xFFFFu)) << 16;
  return (a.f + b.f) + (c.f + d.f);
}

__global__ void k_zero(u32x4* p, int n) {
  int i = blockIdx.x * blockDim.x + threadIdx.x;
  if (i < n) p[i] = (u32x4){0u, 0u, 0u, 0u};
}

// Poison: parity-1 so slot-2's pre-first-write content reads "not arrived" at t=3.
__global__ void k_fill(u32x4* p, int n) {
  int i = blockIdx.x * blockDim.x + threadIdx.x;
  if (i < n) p[i] = (u32x4){0x80008000u, 0x80008000u, 0x80008000u, 0x80008000u};
}

__global__ void k_prep_init(const float* __restrict__ il, float* __restrict__ ip) {
  __shared__ float red[1024];
  int tid = threadIdx.x;
  float m = -1e30f;
  for (int q = tid; q < QQ; q += 1024) m = fmaxf(m, il[q]);
  red[tid] = m; __syncthreads();
  for (int off = 512; off > 0; off >>= 1) {
    if (tid < off) red[tid] = fmaxf(red[tid], red[tid + off]);
    __syncthreads();
  }
  m = red[0]; __syncthreads();
  float s = 0.f;
  for (int q = tid; q < QQ; q += 1024) s += expf(il[q] - m);
  red[tid] = s; __syncthreads();
  for (int off = 512; off > 0; off >>= 1) {
    if (tid < off) red[tid] += red[tid + off];
    __syncthreads();
  }
  s = red[0];
  float inv = 1.0f / s;
  for (int q = tid; q < QQ; q += 1024) ip[q] = expf(il[q] - m) * inv;
}

__global__ void k_prep_B(const float* __restrict__ bl, float* __restrict__ bt) {
  int q = blockIdx.x * blockDim.x + threadIdx.x;
  if (q >= QQ) return;
  const float* row = bl + (size_t)q * SS;
  float m = -1e30f;
  for (int c = 0; c < SS; ++c) m = fmaxf(m, row[c]);
  float s = 0.f;
  for (int c = 0; c < SS; ++c) s += expf(row[c] - m);
  float inv = 1.0f / s;
  for (int c = 0; c < SS; ++c) bt[c * BTS + q] = expf(row[c] - m) * inv;
}

// Row r of A -> column r of A^T[n][k] (bf16), K-stride KP (pads stay zero)
__global__ void k_prep_A(const float* __restrict__ al, unsigned short* __restrict__ at) {
  int r = blockIdx.x;
  const float* row = al + (size_t)r * QQ;
  __shared__ float red[256];
  int tid = threadIdx.x;
  float m = -1e30f;
  for (int n = tid; n < QQ; n += 256) m = fmaxf(m, row[n]);
  red[tid] = m; __syncthreads();
  for (int off = 128; off > 0; off >>= 1) {
    if (tid < off) red[tid] = fmaxf(red[tid], red[tid + off]);
    __syncthreads();
  }
  m = red[0]; __syncthreads();
  float s = 0.f;
  for (int n = tid; n < QQ; n += 256) s += expf(row[n] - m);
  red[tid] = s; __syncthreads();
  for (int off = 128; off > 0; off >>= 1) {
    if (tid < off) red[tid] += red[tid + off];
    __syncthreads();
  }
  s = red[0];
  float inv = 1.0f / s;
  for (int n = tid; n < QQ; n += 256) at[(size_t)n * KP + r] = f2bf(expf(row[n] - m) * inv);
}

// f0 = init * E[:,0] into slot 0, [col-quad][batch-row] layout, parity 0.
__global__ void k_init_step(const int* __restrict__ seq, const float* __restrict__ ip,
                            const float* __restrict__ Bt, unsigned short* __restrict__ buf0) {
  int b = blockIdx.x, tid = threadIdx.x;
  int bb = b >> 4, brow = b & 15;
  int c0 = seq[b * TT];
  unsigned short* dst = buf0 + (size_t)bb * TOTQ * 4;
  for (int q = tid; q < NP; q += 256)
    dst[(size_t)((q >> 2) * MB + brow) * 4 + (q & 3)] = f2bf(ip[q] * Bt[c0 * BTS + q]);
}

__global__ __launch_bounds__(CBLK, 1) void k_hmm_coop(
    const int* __restrict__ seq, const unsigned short* __restrict__ At,
    const float* __restrict__ Bt, unsigned short* __restrict__ bufB,
    float* __restrict__ out) {
  __shared__ u64 aldsq[2][MB * LQ];       // 70 KB: double-buffered alpha (bf16)
  __shared__ float srowF[MB];

  const int tid = threadIdx.x, wg = blockIdx.x;
  const int bb = wg % NBB, sl = wg / NBB;
  const int lane = tid & 63, wv = tid >> 6;
  const int lrow = lane >> 4, lcol = lane & 15;
  const int n0w = (sl * NWV + wv) * 16;

  // LDS K-pad (u64 cols 260..263, rows 0..15, both buffers): zero once
  if (tid < 128) aldsq[tid >> 6][((tid >> 2) & 15) * LQ + 260 + (tid & 3)] = 0;

  // step-invariant At fragments (compiler may stream/remat — measured neutral)
  u32x4 atr[KSTEPS];
  {
    const u32x4* atp = (const u32x4*)(At + (size_t)(n0w + lcol) * KP + 8 * lrow);
#pragma unroll
    for (int ks = 0; ks < KSTEPS; ++ks) atr[ks] = atp[4 * ks];
  }
  const u32x4 ones4 = (u32x4){0x3F803F80u, 0x3F803F80u, 0x3F803F80u, 0x3F803F80u};

  const bool has7 = (tid < PREM);
  float ll = 0.f;

  for (int t = 1; t < TT; ++t) {
    const int rd = (t - 1) % 3, wri = t % 3;
    const unsigned par = (unsigned)((t - 1) & 1);
    const u64 wtag = (u64)(unsigned)(t & 1) << 15;
    const u64* ain = (const u64*)bufB + (size_t)rd * BUFQ + (size_t)bb * TOTQ;
    u64* wbuf8 = (u64*)bufB + (size_t)wri * BUFQ + (size_t)bb * TOTQ;
    u64* buf = aldsq[t & 1];

    // --- fast bulk issue: 16B volatile loads (may be stale; parity-verified)
    u64 av[14];
    {
      const u32x4* vp = (const u32x4*)ain;
#pragma unroll
      for (int j = 0; j < PFULL; ++j) {
        u32x4 v = *(volatile const u32x4*)(vp + tid + j * CBLK);
        av[2 * j] = (u64)v[0] | ((u64)v[1] << 32);
        av[2 * j + 1] = (u64)v[2] | ((u64)v[3] << 32);
      }
      if (has7) {
        u32x4 v = *(volatile const u32x4*)(vp + PFULL * CBLK + tid);
        av[12] = (u64)v[0] | ((u64)v[1] << 32);
        av[13] = (u64)v[2] | ((u64)v[3] << 32);
      }
    }
    // off-critical-path: emission quad (independent of exchange)
    const int ch = seq[(bb * MB + lcol) * TT + t];
    const f32x4 ev = *(const f32x4*)(Bt + (size_t)ch * BTS + n0w + 4 * lrow);

    // --- round-parallel parity verify; escalate to agent atomics after 8
    // rounds so stale caches can never hang the poll.
    {
      unsigned pend = has7 ? 0x3FFFu : 0x0FFFu;
      int round = 0;
      while (true) {
        unsigned np = 0;
#pragma unroll
        for (int w = 0; w < 14; ++w)
          if ((pend >> w) & 1u)
            if ((unsigned)((av[w] >> 15) & 1ull) != par) np |= 1u << w;
        if (!np) break;
        __builtin_amdgcn_s_sleep(1);
        ++round;
        const bool esc = (round >= 8);
#pragma unroll
        for (int w = 0; w < 14; ++w)
          if ((np >> w) & 1u) {
            int idx = (w < 12) ? (2 * (tid + (w >> 1) * CBLK) + (w & 1))
                               : (2 * (PFULL * CBLK + tid) + (w & 1));
            av[w] = esc ? ald8(ain + idx) : *(volatile const u64*)(ain + idx);
          }
        pend = np;
      }
    }

    // --- stage into LDS [brow][cq] (pair p -> rows 2p&15,+1 at col p>>3)
#pragma unroll
    for (int j = 0; j < PFULL; ++j) {
      int p = tid + j * CBLK;
      int brow = (2 * p) & 15, cq = p >> 3;
      buf[brow * LQ + cq] = av[2 * j] & SMASK;
      buf[(brow + 1) * LQ + cq] = av[2 * j + 1] & SMASK;
    }
    if (has7) {
      int p = PFULL * CBLK + tid;
      int brow = (2 * p) & 15, cq = p >> 3;
      buf[brow * LQ + cq] = av[12] & SMASK;
      buf[(brow + 1) * LQ + cq] = av[13] & SMASK;
    }
    __syncthreads();  // LDS alpha ready (also re-aligns waves across steps)

    // --- k-loop: each ds_read feeds the GEMM MFMA and the ones-row-sum MFMA
    const u32x4* ap = ((const u32x4*)buf) + lcol * (LQ / 2) + lrow;
    f32x4 acc = (f32x4){0.f, 0.f, 0.f, 0.f};
    f32x4 accs = (f32x4){0.f, 0.f, 0.f, 0.f};
#pragma unroll
    for (int ks = 0; ks < KSTEPS; ++ks) {
      u32x4 af = ap[4 * ks];
      acc = __builtin_amdgcn_mfma_f32_16x16x32_bf16(
          __builtin_bit_cast(bf16x8, atr[ks]), __builtin_bit_cast(bf16x8, af),
          acc, 0, 0, 0);
      accs = __builtin_amdgcn_mfma_f32_16x16x32_bf16(
          __builtin_bit_cast(bf16x8, ones4), __builtin_bit_cast(bf16x8, af),
          accs, 0, 0, 0);
    }

    // --- epilogue: s in-register; single coalesced self-tagged store/lane
    const float s = accs[0];
    const float inv = 1.0f / s;
    if (sl == 0 && wv == 0) ll += logf(s);

    u64 hv = 0;
#pragma unroll
    for (int i = 0; i < 4; ++i) {
      float v = acc[i] * ev[i] * inv;     // v >= 0, sign bit clear
      hv |= ((u64)f2bf(v) | wtag) << (16 * i);
    }
    // [col-quad][brow] layout: lanes of one wave write 1 KB contiguous
    ast8(wbuf8 + (size_t)(((n0w >> 2) + lrow) * MB + lcol), hv);
    // no tail barrier: next step stages into the other LDS buffer
  }

  // --- final: sl==0 WGs sum alpha_{T-1} (parity (TT-1)&1) and write out
  if (sl == 0) {
    if (tid < MB) srowF[tid] = 0.f;
    __syncthreads();
    const int fs = (TT - 1) % 3;
    const unsigned parF = (unsigned)((TT - 1) & 1);
    const u64* ain = (const u64*)bufB + (size_t)fs * BUFQ + (size_t)bb * TOTQ;
#pragma unroll
    for (int j = 0; j < 13; ++j) {
      int g = tid + j * CBLK;
      u64 q = ald8(ain + g);
      while ((unsigned)((q >> 15) & 1ull) != parF) {
        __builtin_amdgcn_s_sleep(1);
        q = ald8(ain + g);
      }
      atomicAdd(&srowF[g & 15], sum4bf(q & SMASK));
    }
    __syncthreads();
    if (wv == 0 && lrow == 0) out[bb * MB + lcol] = ll + logf(srowF[lcol]);
  }
}

extern "C" void kernel_launch(void* const* d_in, const int* in_sizes, int n_in,
                              void* d_out, int out_size, void* d_ws, size_t ws_size,
                              hipStream_t stream) {
  const int* seq = (const int*)d_in[0];
  const float* Al = (const float*)d_in[1];
  const float* Bl = (const float*)d_in[2];
  const float* il = (const float*)d_in[3];
  float* out = (float*)d_out;

  char* ws = (char*)d_ws;
  unsigned short* At = (unsigned short*)ws;               // 1040*1056*2 = 2,196,480
  size_t off_bt = (size_t)NP * KP * 2;
  float* Bt = (float*)(ws + off_bt);                      // 26*1040*4 = 108,160
  size_t off_ip = off_bt + (size_t)SS * BTS * 4;
  float* ip = (float*)(ws + off_ip);                      // 1040*4
  size_t off_buf = off_ip + (size_t)NP * 4;
  unsigned short* bufB = (unsigned short*)(ws + off_buf); // 3*66560*8 = 1,597,440
  size_t total = off_buf + (size_t)3 * BUFQ * 8;
  int n16 = (int)((total + 15) / 16);

  k_zero<<<(n16 + 255) / 256, 256, 0, stream>>>((u32x4*)ws, n16);
  // poison slot 2 so its pre-first-write content reads as "not arrived" at t=3
  int nf = (int)(((size_t)BUFQ * 8) / 16);
  k_fill<<<(nf + 255) / 256, 256, 0, stream>>>(
      (u32x4*)((u64*)bufB + (size_t)2 * BUFQ), nf);
  k_prep_init<<<1, 1024, 0, stream>>>(il, ip);
  k_prep_B<<<(QQ + 255) / 256, 256, 0, stream>>>(Bl, Bt);
  k_prep_A<<<QQ, 256, 0, stream>>>(Al, At);
  k_init_step<<<NB, 256, 0, stream>>>(seq, ip, Bt, bufB);

  void* args[] = {(void*)&seq, (void*)&At, (void*)&Bt, (void*)&bufB, (void*)&out};
  hipLaunchCooperativeKernel((void*)k_hmm_coop, dim3(NBB * NSL), dim3(CBLK),
                             args, 0, stream);
}

// Round 17
// 1836.749 us; speedup vs baseline: 1.3945x; 1.3945x over previous
//
#include <hip/hip_runtime.h>
#include <math.h>

typedef __bf16 bf16x8 __attribute__((ext_vector_type(8)));
typedef float f32x4 __attribute__((ext_vector_type(4)));
typedef unsigned int u32x4 __attribute__((ext_vector_type(4)));
typedef unsigned long long u64;

constexpr int QQ = 1027;   // states
constexpr int SS = 26;     // alphabet
constexpr int TT = 512;    // sequence length
constexpr int NB = 256;    // batch
constexpr int KP = 1056;   // K padded in LDS (33 ksteps of 32)
constexpr int NP = 1040;   // N padded (65 tiles of 16) = exchanged row length
constexpr int BTS = 1040;  // Bt row stride (floats)
constexpr int NSL = 13;    // N slices (5 tiles = 80 cols each)
constexpr int NBB = 16;    // batch blocks
constexpr int MB = 16;     // batch rows per block
constexpr int NWV = 5;     // waves per WG (1 col-tile each)
constexpr int CBLK = NWV * 64;       // 320
constexpr int KSTEPS = 33;
constexpr int BSQ = NP / 4;          // 260 u64 col-quads per batch row
constexpr int TOTQ = MB * BSQ;       // 4160 u64 per batch-block alpha
constexpr int BUFQ = NBB * TOTQ;     // 66560 u64 per slot
constexpr int LQ = 274;              // u64 LDS row stride
constexpr int NLD = TOTQ / CBLK;     // 13 loads per thread, exact
constexpr u64 SMASK = 0x7FFF7FFF7FFF7FFFull;

__device__ __forceinline__ unsigned short f2bf(float f) {
  union { float f; unsigned u; } v; v.f = f;
  return (unsigned short)((v.u + 0x7fffu + ((v.u >> 16) & 1u)) >> 16);
}

__device__ __forceinline__ u64 ald8(const u64* p) {
  return __hip_atomic_load((u64*)p, __ATOMIC_RELAXED, __HIP_MEMORY_SCOPE_AGENT);
}
__device__ __forceinline__ void ast8(u64* p, u64 v) {
  __hip_atomic_store(p, v, __ATOMIC_RELAXED, __HIP_MEMORY_SCOPE_AGENT);
}

__device__ __forceinline__ float sum4bf(u64 q) {
  union { unsigned u; float f; } a, b, c, d;
  a.u = ((unsigned)(q & 0xFFFFu)) << 16;
  b.u = ((unsigned)((q >> 16) & 0xFFFFu)) << 16;
  c.u = ((unsigned)((q >> 32) & 0xFFFFu)) << 16;
  d.u = ((unsigned)((q >> 48) & 0xFFFFu)) << 16;
  return (a.f + b.f) + (c.f + d.f);
}

__global__ void k_zero(u32x4* p, int n) {
  int i = blockIdx.x * blockDim.x + threadIdx.x;
  if (i < n) p[i] = (u32x4){0u, 0u, 0u, 0u};
}

// Poison: parity-1 so slot-2's pre-first-write content reads "not arrived" at t=3.
__global__ void k_fill(u32x4* p, int n) {
  int i = blockIdx.x * blockDim.x + threadIdx.x;
  if (i < n) p[i] = (u32x4){0x80008000u, 0x80008000u, 0x80008000u, 0x80008000u};
}

__global__ void k_prep_init(const float* __restrict__ il, float* __restrict__ ip) {
  __shared__ float red[1024];
  int tid = threadIdx.x;
  float m = -1e30f;
  for (int q = tid; q < QQ; q += 1024) m = fmaxf(m, il[q]);
  red[tid] = m; __syncthreads();
  for (int off = 512; off > 0; off >>= 1) {
    if (tid < off) red[tid] = fmaxf(red[tid], red[tid + off]);
    __syncthreads();
  }
  m = red[0]; __syncthreads();
  float s = 0.f;
  for (int q = tid; q < QQ; q += 1024) s += expf(il[q] - m);
  red[tid] = s; __syncthreads();
  for (int off = 512; off > 0; off >>= 1) {
    if (tid < off) red[tid] += red[tid + off];
    __syncthreads();
  }
  s = red[0];
  float inv = 1.0f / s;
  for (int q = tid; q < QQ; q += 1024) ip[q] = expf(il[q] - m) * inv;
}

__global__ void k_prep_B(const float* __restrict__ bl, float* __restrict__ bt) {
  int q = blockIdx.x * blockDim.x + threadIdx.x;
  if (q >= QQ) return;
  const float* row = bl + (size_t)q * SS;
  float m = -1e30f;
  for (int c = 0; c < SS; ++c) m = fmaxf(m, row[c]);
  float s = 0.f;
  for (int c = 0; c < SS; ++c) s += expf(row[c] - m);
  float inv = 1.0f / s;
  for (int c = 0; c < SS; ++c) bt[c * BTS + q] = expf(row[c] - m) * inv;
}

// Row r of A -> column r of A^T[n][k] (bf16), K-stride KP (pads stay zero)
__global__ void k_prep_A(const float* __restrict__ al, unsigned short* __restrict__ at) {
  int r = blockIdx.x;
  const float* row = al + (size_t)r * QQ;
  __shared__ float red[256];
  int tid = threadIdx.x;
  float m = -1e30f;
  for (int n = tid; n < QQ; n += 256) m = fmaxf(m, row[n]);
  red[tid] = m; __syncthreads();
  for (int off = 128; off > 0; off >>= 1) {
    if (tid < off) red[tid] = fmaxf(red[tid], red[tid + off]);
    __syncthreads();
  }
  m = red[0]; __syncthreads();
  float s = 0.f;
  for (int n = tid; n < QQ; n += 256) s += expf(row[n] - m);
  red[tid] = s; __syncthreads();
  for (int off = 128; off > 0; off >>= 1) {
    if (tid < off) red[tid] += red[tid + off];
    __syncthreads();
  }
  s = red[0];
  float inv = 1.0f / s;
  for (int n = tid; n < QQ; n += 256) at[(size_t)n * KP + r] = f2bf(expf(row[n] - m) * inv);
}

// f0 = init * E[:,0] into slot 0, [col-quad][batch-row] layout, parity 0.
__global__ void k_init_step(const int* __restrict__ seq, const float* __restrict__ ip,
                            const float* __restrict__ Bt, unsigned short* __restrict__ buf0) {
  int b = blockIdx.x, tid = threadIdx.x;
  int bb = b >> 4, brow = b & 15;
  int c0 = seq[b * TT];
  unsigned short* dst = buf0 + (size_t)bb * TOTQ * 4;
  for (int q = tid; q < NP; q += 256)
    dst[(size_t)((q >> 2) * MB + brow) * 4 + (q & 3)] = f2bf(ip[q] * Bt[c0 * BTS + q]);
}

__global__ __launch_bounds__(CBLK, 1) void k_hmm_coop(
    const int* __restrict__ seq, const unsigned short* __restrict__ At,
    const float* __restrict__ Bt, unsigned short* __restrict__ bufB,
    float* __restrict__ out) {
  __shared__ u64 aldsq[2][MB * LQ];       // 70 KB: double-buffered alpha (bf16)
  __shared__ float srowF[MB];

  const int tid = threadIdx.x, wg = blockIdx.x;
  const int bb = wg % NBB, sl = wg / NBB; // 13 slice-WGs per batch block
  const int lane = tid & 63, wv = tid >> 6;
  const int lrow = lane >> 4, lcol = lane & 15;
  const int n0w = (sl * NWV + wv) * 16;   // this wave's 16-col tile base

  // LDS K-pad (u64 cols 260..263, rows 0..15, both buffers): zero once
  if (tid < 128) aldsq[tid >> 6][((tid >> 2) & 15) * LQ + 260 + (tid & 3)] = 0;

  // step-invariant At fragments
  u32x4 atr[KSTEPS];
  {
    const u32x4* atp = (const u32x4*)(At + (size_t)(n0w + lcol) * KP + 8 * lrow);
#pragma unroll
    for (int ks = 0; ks < KSTEPS; ++ks) atr[ks] = atp[4 * ks];
  }
  const u32x4 ones4 = (u32x4){0x3F803F80u, 0x3F803F80u, 0x3F803F80u, 0x3F803F80u};

  float ll = 0.f;

  for (int t = 1; t < TT; ++t) {
    const int rd = (t - 1) % 3, wri = t % 3;
    const unsigned par = (unsigned)((t - 1) & 1);   // expected parity of inputs
    const u64 wtag = (u64)(unsigned)(t & 1) << 15;  // sign bit for our outputs
    const u64* ain = (const u64*)bufB + (size_t)rd * BUFQ + (size_t)bb * TOTQ;
    u64* wbuf8 = (u64*)bufB + (size_t)wri * BUFQ + (size_t)bb * TOTQ;
    u64* buf = aldsq[t & 1];

    // off-critical-path: emission quad (L2-resident, no exchange dependency)
    const int ch = seq[(bb * MB + lcol) * TT + t];
    const f32x4 ev = *(const f32x4*)(Bt + (size_t)ch * BTS + n0w + 4 * lrow);

    // --- self-tagged alpha loads: issue all 13 coherent (agent-scope) loads
    // with full MLP, then round-parallel re-poll (1 L3 RT per round).
    u64 av[NLD];
    const u64* asrc = ain + tid;
#pragma unroll
    for (int j = 0; j < NLD; ++j) av[j] = ald8(asrc + j * CBLK);
    unsigned pend = (1u << NLD) - 1;
    while (true) {
      unsigned np = 0;
#pragma unroll
      for (int j = 0; j < NLD; ++j)
        if ((pend >> j) & 1u)
          if ((unsigned)((av[j] >> 15) & 1ull) != par) np |= 1u << j;
      if (!np) break;
      __builtin_amdgcn_s_sleep(1);
#pragma unroll
      for (int j = 0; j < NLD; ++j)
        if ((np >> j) & 1u) av[j] = ald8(asrc + j * CBLK);
      pend = np;
    }
#pragma unroll
    for (int j = 0; j < NLD; ++j) av[j] &= SMASK;

    // --- stage into LDS: global g = cq*16 + brow  ->  LDS [brow][cq]
#pragma unroll
    for (int j = 0; j < NLD; ++j) {
      int g = tid + j * CBLK;
      buf[(g & 15) * LQ + (g >> 4)] = av[j];
    }
    __syncthreads();  // LDS alpha ready (single barrier per step)

    // --- k-loop: each ds_read feeds the GEMM MFMA and the ones-row-sum MFMA
    const u32x4* ap = ((const u32x4*)buf) + lcol * (LQ / 2) + lrow;
    f32x4 acc = (f32x4){0.f, 0.f, 0.f, 0.f};
    f32x4 accs = (f32x4){0.f, 0.f, 0.f, 0.f};
#pragma unroll
    for (int ks = 0; ks < KSTEPS; ++ks) {
      u32x4 af = ap[4 * ks];
      acc = __builtin_amdgcn_mfma_f32_16x16x32_bf16(
          __builtin_bit_cast(bf16x8, atr[ks]), __builtin_bit_cast(bf16x8, af),
          acc, 0, 0, 0);
      accs = __builtin_amdgcn_mfma_f32_16x16x32_bf16(
          __builtin_bit_cast(bf16x8, ones4), __builtin_bit_cast(bf16x8, af),
          accs, 0, 0, 0);
    }

    // --- epilogue: s in-register; coalesced self-tagged store (512B/wave)
    const float s = accs[0];              // = sum_k f[lcol][k]
    const float inv = 1.0f / s;
    if (sl == 0 && wv == 0) ll += logf(s);

    u64 hv = 0;
#pragma unroll
    for (int i = 0; i < 4; ++i) {
      float v = acc[i] * ev[i] * inv;     // v >= 0, sign bit clear
      hv |= ((u64)f2bf(v) | wtag) << (16 * i);
    }
    ast8(wbuf8 + (size_t)(((n0w >> 2) + lrow) * MB + lcol), hv);
    // no tail barrier: next step stages into the other LDS buffer
  }

  // --- final: sl==0 WGs sum alpha_{T-1} (parity (TT-1)&1) and write out
  if (sl == 0) {
    if (tid < MB) srowF[tid] = 0.f;
    __syncthreads();
    const int fs = (TT - 1) % 3;
    const unsigned parF = (unsigned)((TT - 1) & 1);
    const u64* ain = (const u64*)bufB + (size_t)fs * BUFQ + (size_t)bb * TOTQ;
#pragma unroll
    for (int j = 0; j < NLD; ++j) {
      int g = tid + j * CBLK;
      u64 q = ald8(ain + g);
      while ((unsigned)((q >> 15) & 1ull) != parF) {
        __builtin_amdgcn_s_sleep(1);
        q = ald8(ain + g);
      }
      atomicAdd(&srowF[g & 15], sum4bf(q & SMASK));
    }
    __syncthreads();
    if (wv == 0 && lrow == 0) out[bb * MB + lcol] = ll + logf(srowF[lcol]);
  }
}

extern "C" void kernel_launch(void* const* d_in, const int* in_sizes, int n_in,
                              void* d_out, int out_size, void* d_ws, size_t ws_size,
                              hipStream_t stream) {
  const int* seq = (const int*)d_in[0];
  const float* Al = (const float*)d_in[1];
  const float* Bl = (const float*)d_in[2];
  const float* il = (const float*)d_in[3];
  float* out = (float*)d_out;

  char* ws = (char*)d_ws;
  unsigned short* At = (unsigned short*)ws;               // 1040*1056*2 = 2,196,480
  size_t off_bt = (size_t)NP * KP * 2;
  float* Bt = (float*)(ws + off_bt);                      // 26*1040*4 = 108,160
  size_t off_ip = off_bt + (size_t)SS * BTS * 4;
  float* ip = (float*)(ws + off_ip);                      // 1040*4
  size_t off_buf = off_ip + (size_t)NP * 4;
  unsigned short* bufB = (unsigned short*)(ws + off_buf); // 3*66560*8 = 1,597,440
  size_t total = off_buf + (size_t)3 * BUFQ * 8;
  int n16 = (int)((total + 15) / 16);

  k_zero<<<(n16 + 255) / 256, 256, 0, stream>>>((u32x4*)ws, n16);
  // poison slot 2 so its pre-first-write content reads as "not arrived" at t=3
  int nf = (int)(((size_t)BUFQ * 8) / 16);
  k_fill<<<(nf + 255) / 256, 256, 0, stream>>>(
      (u32x4*)((u64*)bufB + (size_t)2 * BUFQ), nf);
  k_prep_init<<<1, 1024, 0, stream>>>(il, ip);
  k_prep_B<<<(QQ + 255) / 256, 256, 0, stream>>>(Bl, Bt);
  k_prep_A<<<QQ, 256, 0, stream>>>(Al, At);
  k_init_step<<<NB, 256, 0, stream>>>(seq, ip, Bt, bufB);

  void* args[] = {(void*)&seq, (void*)&At, (void*)&Bt, (void*)&bufB, (void*)&out};
  hipLaunchCooperativeKernel((void*)k_hmm_coop, dim3(NBB * NSL), dim3(CBLK),
                             args, 0, stream);
}